// Round 1
// baseline (13403.674 us; speedup 1.0000x reference)
//
#include <hip/hip_runtime.h>
#include <hip/hip_bf16.h>
#include <stdint.h>

// ---------------------------------------------------------------------------
// BiLSTM (H=256, fwd+rev) -> sentence LSTM (512->512) -> linear -> CRF(16)
// B=256 sentences, T=128 words, F=768. Output: scalar log-likelihood (fp32).
//
// Round 1: correctness-first bf16 MFMA pipeline.
//   phase 1: fp32->bf16 converts (x + 6 weight matrices)
//   phase 2: gemm_bt  gx[32768,2048] = x_bf16[32768,768] @ [w_ih_f;w_ih_r]^T
//   phase 3: lstm_fr  16 blocks x 32 batch rows, streams W_hh from L2 per step
//   phase 4: gemm_bt  gs[32768,2048] = h_cat[32768,512] @ w_ih_s^T  (gs aliases gx)
//   phase 5: lstm_s   16 blocks x 16 batch rows, streams W_hh_s (2MB) per step
//   phase 6: emissions + single-wave CRF forward algorithm (fp32)
// Workspace ~193 MB (gs aliases gx, h_cat aliases x_bf16).
// ---------------------------------------------------------------------------

typedef __bf16 bf16_t;
typedef __bf16 bf16x8 __attribute__((ext_vector_type(8)));
typedef __bf16 bf16x4v __attribute__((ext_vector_type(4)));
typedef float f32x4 __attribute__((ext_vector_type(4)));

#define MFMA_BF16(a, b, c) __builtin_amdgcn_mfma_f32_16x16x32_bf16((a), (b), (c), 0, 0, 0)

__device__ __forceinline__ float sigm_(float x) { return 1.f / (1.f + __expf(-x)); }
__device__ __forceinline__ float tanh_(float x) {
  x = fminf(20.f, fmaxf(-20.f, x));           // avoid inf/inf NaN
  float e = __expf(-2.f * x);
  return (1.f - e) / (1.f + e);
}

// ---------------------------- fp32 -> bf16 convert -------------------------
__global__ void cvt4(const float* __restrict__ in, bf16_t* __restrict__ out, int n4) {
  int i = blockIdx.x * blockDim.x + threadIdx.x;
  int stride = gridDim.x * blockDim.x;
  for (; i < n4; i += stride) {
    float4 v = ((const float4*)in)[i];
    bf16x4v o;
    o.x = (bf16_t)v.x; o.y = (bf16_t)v.y; o.z = (bf16_t)v.z; o.w = (bf16_t)v.w;
    ((bf16x4v*)out)[i] = o;
  }
}

// ------------------------------- bf16 GEMM ---------------------------------
// C[M,N] = A[M,K] @ B[N,K]^T, all bf16 row-major (K-contiguous), fp32 accum.
// 128x128 tile, BK=64, 4 waves (2x2), each wave 64x64 via 4x4 MFMA 16x16x32.
// LDS rows padded +8 bf16: row stride 144B -> (r+c)%8 bank groups, 2-way = free.
__global__ void __launch_bounds__(256, 2)
gemm_bt(const bf16_t* __restrict__ A, const bf16_t* __restrict__ B,
        bf16_t* __restrict__ C, int M, int N, int K) {
  const int tid = threadIdx.x;
  const int w = tid >> 6, lane = tid & 63, quad = lane >> 4, l15 = lane & 15;
  const int ntiles = N >> 7;
  const int m0 = (blockIdx.x / ntiles) << 7;
  const int n0 = (blockIdx.x % ntiles) << 7;
  const int wm = (w >> 1) << 6, wn = (w & 1) << 6;

  __shared__ bf16_t As[128 * 72];
  __shared__ bf16_t Bs[128 * 72];

  const f32x4 z4 = {0.f, 0.f, 0.f, 0.f};
  f32x4 acc[4][4];
#pragma unroll
  for (int i = 0; i < 4; ++i)
#pragma unroll
    for (int j = 0; j < 4; ++j) acc[i][j] = z4;

  const int nk = K >> 6;
  for (int kt = 0; kt < nk; ++kt) {
    uint4 av[4], bv[4];
#pragma unroll
    for (int i = 0; i < 4; ++i) {
      int cid = tid + i * 256;            // 0..1023 = 128 rows x 8 chunks(16B)
      int r = cid >> 3, c = cid & 7;
      av[i] = *(const uint4*)&A[(size_t)(m0 + r) * K + kt * 64 + c * 8];
      bv[i] = *(const uint4*)&B[(size_t)(n0 + r) * K + kt * 64 + c * 8];
    }
    __syncthreads();                      // prev compute done (WAR)
#pragma unroll
    for (int i = 0; i < 4; ++i) {
      int cid = tid + i * 256;
      int r = cid >> 3, c = cid & 7;
      *(uint4*)&As[r * 72 + c * 8] = av[i];
      *(uint4*)&Bs[r * 72 + c * 8] = bv[i];
    }
    __syncthreads();
#pragma unroll
    for (int s = 0; s < 2; ++s) {
      bf16x8 af[4], bfr[4];
#pragma unroll
      for (int i = 0; i < 4; ++i)
        af[i] = *(const bf16x8*)&As[(wm + i * 16 + l15) * 72 + s * 32 + quad * 8];
#pragma unroll
      for (int j = 0; j < 4; ++j)
        bfr[j] = *(const bf16x8*)&Bs[(wn + j * 16 + l15) * 72 + s * 32 + quad * 8];
#pragma unroll
      for (int i = 0; i < 4; ++i)
#pragma unroll
        for (int j = 0; j < 4; ++j)
          acc[i][j] = MFMA_BF16(af[i], bfr[j], acc[i][j]);
    }
  }
  // epilogue: D row = quad*4+reg, col = lane&15
#pragma unroll
  for (int i = 0; i < 4; ++i)
#pragma unroll
    for (int j = 0; j < 4; ++j)
#pragma unroll
      for (int p = 0; p < 4; ++p) {
        int row = m0 + wm + i * 16 + quad * 4 + p;
        int col = n0 + wn + j * 16 + l15;
        C[(size_t)row * N + col] = (bf16_t)acc[i][j][p];
      }
}

// ----------------------- fwd/rev LSTM recurrence ---------------------------
// grid 16: dir = bx>>3, 32 batch rows per block. Wave w owns hidden [w*64,w*64+64)
// (all 4 gates for those hidden -> no cross-wave exchange; c in regs, h in LDS).
__global__ void __launch_bounds__(256, 1)
lstm_fr(const bf16_t* __restrict__ gx, const bf16_t* __restrict__ whh,
        const float* __restrict__ b_f, const float* __restrict__ b_r,
        bf16_t* __restrict__ h_cat) {
  const int tid = threadIdx.x;
  const int w = tid >> 6, lane = tid & 63, quad = lane >> 4, l15 = lane & 15;
  const int dir = blockIdx.x >> 3;
  const int rows0 = (blockIdx.x & 7) << 5;
  const int hid0 = w << 6;
  const bf16_t* W = whh + (size_t)dir * 1024 * 256;
  const float* bias = dir ? b_r : b_f;

  __shared__ bf16_t hs[2][32][264];       // 264 = 256+8 pad (bank spread)
  for (int idx = tid; idx < 2 * 32 * 264; idx += 256) (&hs[0][0][0])[idx] = (bf16_t)0.f;

  float br[4][4];
#pragma unroll
  for (int g = 0; g < 4; ++g)
#pragma unroll
    for (int ht = 0; ht < 4; ++ht) br[g][ht] = bias[g * 256 + hid0 + ht * 16 + l15];

  const f32x4 z4 = {0.f, 0.f, 0.f, 0.f};
  f32x4 cst[2][4];
#pragma unroll
  for (int mi = 0; mi < 2; ++mi)
#pragma unroll
    for (int ht = 0; ht < 4; ++ht) cst[mi][ht] = z4;

  __syncthreads();

  for (int t = 0; t < 128; ++t) {
    const int tt = dir ? (127 - t) : t;
    const int cur = t & 1, nxt = cur ^ 1;

    f32x4 acc[4][4][2];
#pragma unroll
    for (int g = 0; g < 4; ++g)
#pragma unroll
      for (int ht = 0; ht < 4; ++ht) {
        acc[g][ht][0] = z4;
        acc[g][ht][1] = z4;
      }

    for (int ks = 0; ks < 8; ++ks) {      // K = 256
      bf16x8 a0 = *(const bf16x8*)&hs[cur][l15][ks * 32 + quad * 8];
      bf16x8 a1 = *(const bf16x8*)&hs[cur][16 + l15][ks * 32 + quad * 8];
#pragma unroll
      for (int g = 0; g < 4; ++g)
#pragma unroll
        for (int ht = 0; ht < 4; ++ht) {
          bf16x8 bfr = *(const bf16x8*)&W[(size_t)(g * 256 + hid0 + ht * 16 + l15) * 256 +
                                          ks * 32 + quad * 8];
          acc[g][ht][0] = MFMA_BF16(a0, bfr, acc[g][ht][0]);
          acc[g][ht][1] = MFMA_BF16(a1, bfr, acc[g][ht][1]);
        }
    }

#pragma unroll
    for (int mi = 0; mi < 2; ++mi)
#pragma unroll
      for (int ht = 0; ht < 4; ++ht)
#pragma unroll
        for (int p = 0; p < 4; ++p) {
          const int row = rows0 + mi * 16 + quad * 4 + p;     // batch index
          const int hid = hid0 + ht * 16 + l15;
          const size_t gb = ((size_t)row * 128 + tt) * 2048 + (size_t)dir * 1024 + hid;
          float Pi = acc[0][ht][mi][p] + (float)gx[gb] + br[0][ht];
          float Pf = acc[1][ht][mi][p] + (float)gx[gb + 256] + br[1][ht];
          float Pg = acc[2][ht][mi][p] + (float)gx[gb + 512] + br[2][ht];
          float Po = acc[3][ht][mi][p] + (float)gx[gb + 768] + br[3][ht];
          float cc = cst[mi][ht][p];
          cc = sigm_(Pf) * cc + sigm_(Pi) * tanh_(Pg);
          cst[mi][ht][p] = cc;
          float hv = sigm_(Po) * tanh_(cc);
          hs[nxt][mi * 16 + quad * 4 + p][hid] = (bf16_t)hv;
          h_cat[((size_t)row * 128 + tt) * 512 + dir * 256 + hid] = (bf16_t)hv;
        }
    __syncthreads();
  }
}

// ------------------------ sentence LSTM recurrence -------------------------
// grid 16: 16 batch rows per block; wave w owns hidden [w*128, w*128+128).
__global__ void __launch_bounds__(256, 1)
lstm_s(const bf16_t* __restrict__ gs, const bf16_t* __restrict__ wsh,
       const float* __restrict__ b_s, float* __restrict__ hT) {
  const int tid = threadIdx.x;
  const int w = tid >> 6, lane = tid & 63, quad = lane >> 4, l15 = lane & 15;
  const int rows0 = blockIdx.x << 4;
  const int hid0 = w << 7;

  __shared__ bf16_t hs[2][16][520];       // 520 = 512+8 pad
  for (int idx = tid; idx < 2 * 16 * 520; idx += 256) (&hs[0][0][0])[idx] = (bf16_t)0.f;

  float br[4][8];
#pragma unroll
  for (int g = 0; g < 4; ++g)
#pragma unroll
    for (int ht = 0; ht < 8; ++ht) br[g][ht] = b_s[g * 512 + hid0 + ht * 16 + l15];

  const f32x4 z4 = {0.f, 0.f, 0.f, 0.f};
  f32x4 cst[8];
#pragma unroll
  for (int ht = 0; ht < 8; ++ht) cst[ht] = z4;

  __syncthreads();

  for (int t = 0; t < 128; ++t) {
    const int cur = t & 1, nxt = cur ^ 1;
    f32x4 acc[4][8];
#pragma unroll
    for (int g = 0; g < 4; ++g)
#pragma unroll
      for (int ht = 0; ht < 8; ++ht) acc[g][ht] = z4;

    for (int ks = 0; ks < 16; ++ks) {     // K = 512
      bf16x8 a0 = *(const bf16x8*)&hs[cur][l15][ks * 32 + quad * 8];
#pragma unroll
      for (int g = 0; g < 4; ++g)
#pragma unroll
        for (int ht = 0; ht < 8; ++ht) {
          bf16x8 bfr = *(const bf16x8*)&wsh[(size_t)(g * 512 + hid0 + ht * 16 + l15) * 512 +
                                            ks * 32 + quad * 8];
          acc[g][ht] = MFMA_BF16(a0, bfr, acc[g][ht]);
        }
    }

#pragma unroll
    for (int ht = 0; ht < 8; ++ht)
#pragma unroll
      for (int p = 0; p < 4; ++p) {
        const int row = rows0 + quad * 4 + p;
        const int hid = hid0 + ht * 16 + l15;
        const size_t gb = ((size_t)row * 128 + t) * 2048 + hid;
        float Pi = acc[0][ht][p] + (float)gs[gb] + br[0][ht];
        float Pf = acc[1][ht][p] + (float)gs[gb + 512] + br[1][ht];
        float Pg = acc[2][ht][p] + (float)gs[gb + 1024] + br[2][ht];
        float Po = acc[3][ht][p] + (float)gs[gb + 1536] + br[3][ht];
        float cc = cst[ht][p];
        cc = sigm_(Pf) * cc + sigm_(Pi) * tanh_(Pg);
        cst[ht][p] = cc;
        float hv = sigm_(Po) * tanh_(cc);
        hs[nxt][quad * 4 + p][hid] = (bf16_t)hv;
        if (t == 127) hT[(size_t)row * 512 + hid] = hv;   // final hidden, fp32
      }
    __syncthreads();
  }
}

// ------------------------------- emissions ---------------------------------
__global__ void emis_k(const float* __restrict__ hT, const float* __restrict__ lin_w,
                       const float* __restrict__ lin_b, float* __restrict__ em) {
  const int idx = blockIdx.x * 256 + threadIdx.x;   // 4096 = 256 x 16
  const int s = idx >> 4, c = idx & 15;
  const float4* h4 = (const float4*)(hT + (size_t)s * 512);
  const float4* w4 = (const float4*)(lin_w + (size_t)c * 512);
  float acc = lin_b[c];
  for (int k = 0; k < 128; ++k) {
    float4 a = h4[k], b = w4[k];
    acc += a.x * b.x + a.y * b.y + a.z * b.z + a.w * b.w;
  }
  em[idx] = acc;
}

// ---------------------------------- CRF ------------------------------------
// Single wave: lanes = (i = lane&15, jgroup = lane>>4); 256 sequential steps.
__global__ void crf_k(const float* __restrict__ em, const int* __restrict__ y,
                      const float* __restrict__ cs, const float* __restrict__ ce,
                      const float* __restrict__ tr, float* __restrict__ out) {
  __shared__ float alpha[16];
  __shared__ float trs[256];
  const int lane = threadIdx.x;
  const int i = lane & 15, jg = lane >> 4;

  for (int k = lane; k < 256; k += 64) trs[k] = tr[k];
  __syncthreads();

  // numerator partials
  float np = 0.f;
  for (int s = lane; s < 256; s += 64) np += em[s * 16 + y[s]];
  for (int s = lane + 1; s < 256; s += 64) np += trs[y[s - 1] * 16 + y[s]];
#pragma unroll
  for (int off = 32; off > 0; off >>= 1) np += __shfl_down(np, off, 64);

  if (lane < 16) alpha[lane] = cs[lane] + em[lane];
  __syncthreads();

  for (int s = 1; s < 256; ++s) {
    const float* e = em + s * 16;
    float v[4];
#pragma unroll
    for (int jj = 0; jj < 4; ++jj) v[jj] = alpha[i] + trs[i * 16 + (jj * 4 + jg)];
    float res[4];
#pragma unroll
    for (int jj = 0; jj < 4; ++jj) {
      float m = v[jj];
      m = fmaxf(m, __shfl_xor(m, 1, 64));
      m = fmaxf(m, __shfl_xor(m, 2, 64));
      m = fmaxf(m, __shfl_xor(m, 4, 64));
      m = fmaxf(m, __shfl_xor(m, 8, 64));
      float ex = __expf(v[jj] - m);
      ex += __shfl_xor(ex, 1, 64);
      ex += __shfl_xor(ex, 2, 64);
      ex += __shfl_xor(ex, 4, 64);
      ex += __shfl_xor(ex, 8, 64);
      res[jj] = m + __logf(ex) + e[jj * 4 + jg];
    }
#pragma unroll
    for (int jj = 0; jj < 4; ++jj)
      if (i == 0) alpha[jj * 4 + jg] = res[jj];
  }

  float v = (lane < 16) ? (alpha[lane] + ce[lane]) : -3.0e38f;
  float m = v;
#pragma unroll
  for (int off = 32; off > 0; off >>= 1) m = fmaxf(m, __shfl_xor(m, off, 64));
  float ex = __expf(v - m);
#pragma unroll
  for (int off = 32; off > 0; off >>= 1) ex += __shfl_xor(ex, off, 64);
  float denom = m + __logf(ex);

  if (lane == 0) {
    float num = np + cs[y[0]] + ce[y[255]];
    out[0] = num - denom;
  }
}

// ------------------------------ orchestration ------------------------------
extern "C" void kernel_launch(void* const* d_in, const int* in_sizes, int n_in,
                              void* d_out, int out_size, void* d_ws, size_t ws_size,
                              hipStream_t stream) {
  const float* x = (const float*)d_in[0];
  const int* y = (const int*)d_in[1];
  // d_in[2] = mask (all true) -> ignored
  const float* w_ih_f = (const float*)d_in[3];
  const float* w_hh_f = (const float*)d_in[4];
  const float* b_f = (const float*)d_in[5];
  const float* w_ih_r = (const float*)d_in[6];
  const float* w_hh_r = (const float*)d_in[7];
  const float* b_r = (const float*)d_in[8];
  const float* w_ih_s = (const float*)d_in[9];
  const float* w_hh_s = (const float*)d_in[10];
  const float* b_s = (const float*)d_in[11];
  const float* lin_w = (const float*)d_in[12];
  const float* lin_b = (const float*)d_in[13];
  const float* crf_s = (const float*)d_in[14];
  const float* crf_e = (const float*)d_in[15];
  const float* crf_t = (const float*)d_in[16];

  char* ws = (char*)d_ws;
  size_t off = 0;
  auto take = [&](size_t bytes) {
    void* p = ws + off;
    off += (bytes + 255) & ~(size_t)255;
    return p;
  };
  bf16_t* Wx  = (bf16_t*)take((size_t)2048 * 768 * 2);    // [w_ih_f; w_ih_r]
  bf16_t* Whh = (bf16_t*)take((size_t)2 * 1024 * 256 * 2);
  bf16_t* Wsi = (bf16_t*)take((size_t)2048 * 512 * 2);
  bf16_t* Wsh = (bf16_t*)take((size_t)2048 * 512 * 2);
  bf16_t* gx  = (bf16_t*)take((size_t)32768 * 2048 * 2);  // later aliased as gs
  bf16_t* xb  = (bf16_t*)take((size_t)32768 * 768 * 2);   // later aliased as h_cat
  float* hT   = (float*)take((size_t)256 * 512 * 4);
  float* em   = (float*)take((size_t)4096 * 4);
  bf16_t* gs = gx;     // gx dead after lstm_fr
  bf16_t* hcat = xb;   // xb dead after first gemm
  (void)ws_size; (void)in_sizes; (void)n_in; (void)out_size;

  // phase 1: converts
  cvt4<<<2048, 256, 0, stream>>>(x, xb, 32768 * 768 / 4);
  cvt4<<<64, 256, 0, stream>>>(w_ih_f, Wx, 786432 / 4);
  cvt4<<<64, 256, 0, stream>>>(w_ih_r, Wx + 786432, 786432 / 4);
  cvt4<<<32, 256, 0, stream>>>(w_hh_f, Whh, 262144 / 4);
  cvt4<<<32, 256, 0, stream>>>(w_hh_r, Whh + 262144, 262144 / 4);
  cvt4<<<64, 256, 0, stream>>>(w_ih_s, Wsi, 1048576 / 4);
  cvt4<<<64, 256, 0, stream>>>(w_hh_s, Wsh, 1048576 / 4);

  // phase 2: input gates for fwd+rev   (M=32768, N=2048, K=768)
  gemm_bt<<<4096, 256, 0, stream>>>(xb, Wx, gx, 32768, 2048, 768);

  // phase 3: fwd/rev recurrences -> h_cat
  lstm_fr<<<16, 256, 0, stream>>>(gx, Whh, b_f, b_r, hcat);

  // phase 4: sentence input gates     (M=32768, N=2048, K=512)
  gemm_bt<<<4096, 256, 0, stream>>>(hcat, Wsi, gs, 32768, 2048, 512);

  // phase 5: sentence recurrence -> hT
  lstm_s<<<16, 256, 0, stream>>>(gs, Wsh, b_s, hT);

  // phase 6: emissions + CRF
  emis_k<<<16, 256, 0, stream>>>(hT, lin_w, lin_b, em);
  crf_k<<<1, 64, 0, stream>>>(em, y, crf_s, crf_e, crf_t, (float*)d_out);
}

// Round 2
// 5609.520 us; speedup vs baseline: 2.3895x; 2.3895x over previous
//
#include <hip/hip_runtime.h>
#include <hip/hip_bf16.h>
#include <stdint.h>

// ---------------------------------------------------------------------------
// BiLSTM (H=256, fwd+rev) -> sentence LSTM (512->512) -> linear -> CRF(16)
// Round 2: recurrences restructured as 128-block weight-stationary kernels
// with hidden-dim splitting + per-step device-scope grid barrier.
//   lstm_fr: 128 blocks = 2 dir x 8 batch-groups(32 rows) x 8 hid-splits(32)
//            W slice (64KB) LDS-resident; h exchanged via global dbuf.
//   lstm_s : 128 blocks = 8 batch-groups(32 rows) x 16 hid-splits(32)
//            W slice (130KB) LDS-resident.
// Barrier: generation counter, agent-scope atomics, __threadfence for
// cross-XCD L2 writeback/invalidate. Grid 128 <= 256 CUs at 1 block/CU.
// ---------------------------------------------------------------------------

typedef __bf16 bf16_t;
typedef __bf16 bf16x8 __attribute__((ext_vector_type(8)));
typedef __bf16 bf16x4v __attribute__((ext_vector_type(4)));
typedef float f32x4 __attribute__((ext_vector_type(4)));

#define MFMA_BF16(a, b, c) __builtin_amdgcn_mfma_f32_16x16x32_bf16((a), (b), (c), 0, 0, 0)

__device__ __forceinline__ float sigm_(float x) { return 1.f / (1.f + __expf(-x)); }
__device__ __forceinline__ float tanh_(float x) {
  x = fminf(20.f, fmaxf(-20.f, x));
  float e = __expf(-2.f * x);
  return (1.f - e) / (1.f + e);
}

// ------------------------- device-scope grid barrier -----------------------
// Requires all nblk blocks co-resident (grid <= 256, 1 block/CU).
__device__ __forceinline__ void gbar(unsigned* cnt, unsigned* gen, unsigned nblk) {
  __syncthreads();
  if (threadIdx.x == 0) {
    __threadfence();   // release: write back my XCD L2 (publish h-slice)
    unsigned g = __hip_atomic_load(gen, __ATOMIC_RELAXED, __HIP_MEMORY_SCOPE_AGENT);
    if (__hip_atomic_fetch_add(cnt, 1u, __ATOMIC_RELAXED, __HIP_MEMORY_SCOPE_AGENT) == nblk - 1u) {
      __hip_atomic_store(cnt, 0u, __ATOMIC_RELAXED, __HIP_MEMORY_SCOPE_AGENT);
      __hip_atomic_store(gen, g + 1u, __ATOMIC_RELEASE, __HIP_MEMORY_SCOPE_AGENT);
    } else {
      while ((int)(__hip_atomic_load(gen, __ATOMIC_RELAXED, __HIP_MEMORY_SCOPE_AGENT) - g) <= 0) {
        __builtin_amdgcn_s_sleep(1);
      }
    }
    __threadfence();   // acquire: invalidate L1/L2 so we see others' h-slices
  }
  __syncthreads();
}

__global__ void init_bar(unsigned* bar) {
  if (threadIdx.x < 8) bar[threadIdx.x] = 0u;
}

// ---------------------------- fp32 -> bf16 convert -------------------------
__global__ void cvt4(const float* __restrict__ in, bf16_t* __restrict__ out, int n4) {
  int i = blockIdx.x * blockDim.x + threadIdx.x;
  int stride = gridDim.x * blockDim.x;
  for (; i < n4; i += stride) {
    float4 v = ((const float4*)in)[i];
    bf16x4v o;
    o.x = (bf16_t)v.x; o.y = (bf16_t)v.y; o.z = (bf16_t)v.z; o.w = (bf16_t)v.w;
    ((bf16x4v*)out)[i] = o;
  }
}

// ------------------------------- bf16 GEMM ---------------------------------
// C[M,N] = A[M,K] @ B[N,K]^T, bf16 row-major, fp32 accum. 128x128 tile, BK=64.
__global__ void __launch_bounds__(256, 2)
gemm_bt(const bf16_t* __restrict__ A, const bf16_t* __restrict__ B,
        bf16_t* __restrict__ C, int M, int N, int K) {
  const int tid = threadIdx.x;
  const int w = tid >> 6, lane = tid & 63, quad = lane >> 4, l15 = lane & 15;
  const int ntiles = N >> 7;
  const int m0 = (blockIdx.x / ntiles) << 7;
  const int n0 = (blockIdx.x % ntiles) << 7;
  const int wm = (w >> 1) << 6, wn = (w & 1) << 6;

  __shared__ bf16_t As[128 * 72];
  __shared__ bf16_t Bs[128 * 72];

  const f32x4 z4 = {0.f, 0.f, 0.f, 0.f};
  f32x4 acc[4][4];
#pragma unroll
  for (int i = 0; i < 4; ++i)
#pragma unroll
    for (int j = 0; j < 4; ++j) acc[i][j] = z4;

  const int nk = K >> 6;
  for (int kt = 0; kt < nk; ++kt) {
    uint4 av[4], bv[4];
#pragma unroll
    for (int i = 0; i < 4; ++i) {
      int cid = tid + i * 256;
      int r = cid >> 3, c = cid & 7;
      av[i] = *(const uint4*)&A[(size_t)(m0 + r) * K + kt * 64 + c * 8];
      bv[i] = *(const uint4*)&B[(size_t)(n0 + r) * K + kt * 64 + c * 8];
    }
    __syncthreads();
#pragma unroll
    for (int i = 0; i < 4; ++i) {
      int cid = tid + i * 256;
      int r = cid >> 3, c = cid & 7;
      *(uint4*)&As[r * 72 + c * 8] = av[i];
      *(uint4*)&Bs[r * 72 + c * 8] = bv[i];
    }
    __syncthreads();
#pragma unroll
    for (int s = 0; s < 2; ++s) {
      bf16x8 af[4], bfr[4];
#pragma unroll
      for (int i = 0; i < 4; ++i)
        af[i] = *(const bf16x8*)&As[(wm + i * 16 + l15) * 72 + s * 32 + quad * 8];
#pragma unroll
      for (int j = 0; j < 4; ++j)
        bfr[j] = *(const bf16x8*)&Bs[(wn + j * 16 + l15) * 72 + s * 32 + quad * 8];
#pragma unroll
      for (int i = 0; i < 4; ++i)
#pragma unroll
        for (int j = 0; j < 4; ++j)
          acc[i][j] = MFMA_BF16(af[i], bfr[j], acc[i][j]);
    }
  }
#pragma unroll
  for (int i = 0; i < 4; ++i)
#pragma unroll
    for (int j = 0; j < 4; ++j)
#pragma unroll
      for (int p = 0; p < 4; ++p) {
        int row = m0 + wm + i * 16 + quad * 4 + p;
        int col = n0 + wn + j * 16 + l15;
        C[(size_t)row * N + col] = (bf16_t)acc[i][j][p];
      }
}

// ----------------------- fwd/rev LSTM recurrence ---------------------------
// 128 blocks: dir(2) x bg(8, 32 rows) x hsp(8, 32 hid). W slice in LDS.
// hb layout: [buf(2)][dir(2)][256 rows][256 hid] bf16.
__global__ void __launch_bounds__(256, 1)
lstm_fr(const bf16_t* __restrict__ gx, const bf16_t* __restrict__ whh,
        const float* __restrict__ b_f, const float* __restrict__ b_r,
        bf16_t* __restrict__ h_cat, bf16_t* __restrict__ hb,
        unsigned* __restrict__ bar) {
  const int tid = threadIdx.x;
  const int w = tid >> 6, lane = tid & 63, quad = lane >> 4, l15 = lane & 15;
  const int dir = blockIdx.x >> 6;
  const int bg = (blockIdx.x >> 3) & 7;
  const int hsp = blockIdx.x & 7;
  const int rows0 = bg << 5, hid0 = hsp << 5;
  const int mi = w & 1, ni = w >> 1;

  __shared__ bf16_t Ws[128 * 264];   // packed row = g*32+h, K=256, +8 pad
  const bf16_t* Wg = whh + (size_t)dir * 262144;
#pragma unroll
  for (int i = 0; i < 16; ++i) {
    int cid = tid + i * 256;         // 4096 = 128 rows x 32 chunks(16B)
    int r = cid >> 5, c = cid & 31;
    int g = r >> 5, h = r & 31;
    *(uint4*)&Ws[r * 264 + c * 8] = *(const uint4*)&Wg[(size_t)(g * 256 + hid0 + h) * 256 + c * 8];
  }
  const float* bias = dir ? b_r : b_f;
  const int hid = hid0 + ni * 16 + l15;
  float br[4];
#pragma unroll
  for (int g = 0; g < 4; ++g) br[g] = bias[g * 256 + hid];

  // zero own slice of hb[0][dir]
  bf16_t* hb0 = hb + (size_t)dir * 65536;
  for (int i = tid; i < 1024; i += 256)
    hb0[(size_t)(rows0 + (i >> 5)) * 256 + hid0 + (i & 31)] = (bf16_t)0.f;

  float cst[4] = {0.f, 0.f, 0.f, 0.f};
  const f32x4 z4 = {0.f, 0.f, 0.f, 0.f};
  gbar(bar, bar + 1, 128);

  for (int t = 0; t < 128; ++t) {
    const int tt = dir ? 127 - t : t;
    const int cur = t & 1, nxt = cur ^ 1;
    const bf16_t* hr = hb + ((size_t)cur * 2 + dir) * 65536 +
                       (size_t)(rows0 + mi * 16 + l15) * 256;
    f32x4 acc[4];
#pragma unroll
    for (int g = 0; g < 4; ++g) acc[g] = z4;

#pragma unroll
    for (int ks = 0; ks < 8; ++ks) {          // K = 256
      bf16x8 a = *(const bf16x8*)&hr[ks * 32 + quad * 8];
#pragma unroll
      for (int g = 0; g < 4; ++g) {
        bf16x8 b = *(const bf16x8*)&Ws[(g * 32 + ni * 16 + l15) * 264 + ks * 32 + quad * 8];
        acc[g] = MFMA_BF16(a, b, acc[g]);
      }
    }

    const int row = rows0 + mi * 16 + quad * 4;
#pragma unroll
    for (int p = 0; p < 4; ++p) {
      const size_t gb = ((size_t)(row + p) * 128 + tt) * 2048 + (size_t)dir * 1024 + hid;
      float Pi = acc[0][p] + (float)gx[gb] + br[0];
      float Pf = acc[1][p] + (float)gx[gb + 256] + br[1];
      float Pg = acc[2][p] + (float)gx[gb + 512] + br[2];
      float Po = acc[3][p] + (float)gx[gb + 768] + br[3];
      float cc = sigm_(Pf) * cst[p] + sigm_(Pi) * tanh_(Pg);
      cst[p] = cc;
      float hv = sigm_(Po) * tanh_(cc);
      hb[((size_t)nxt * 2 + dir) * 65536 + (size_t)(row + p) * 256 + hid] = (bf16_t)hv;
      h_cat[((size_t)(row + p) * 128 + tt) * 512 + dir * 256 + hid] = (bf16_t)hv;
    }
    gbar(bar, bar + 1, 128);
  }
}

// ------------------------ sentence LSTM recurrence -------------------------
// 128 blocks: bg(8, 32 rows) x hsp(16, 32 hid). W slice (130KB) in LDS.
// hb layout: [buf(2)][256 rows][512 hid] bf16.
__global__ void __launch_bounds__(256, 1)
lstm_s(const bf16_t* __restrict__ gs, const bf16_t* __restrict__ wsh,
       const float* __restrict__ b_s, float* __restrict__ hT,
       bf16_t* __restrict__ hb, unsigned* __restrict__ bar) {
  const int tid = threadIdx.x;
  const int w = tid >> 6, lane = tid & 63, quad = lane >> 4, l15 = lane & 15;
  const int bg = blockIdx.x >> 4;
  const int hsp = blockIdx.x & 15;
  const int rows0 = bg << 5, hid0 = hsp << 5;
  const int mi = w & 1, ni = w >> 1;

  __shared__ bf16_t Ws[128 * 520];   // packed row = g*32+h, K=512, +8 pad
#pragma unroll
  for (int i = 0; i < 32; ++i) {
    int cid = tid + i * 256;         // 8192 = 128 rows x 64 chunks(16B)
    int r = cid >> 6, c = cid & 63;
    int g = r >> 5, h = r & 31;
    *(uint4*)&Ws[r * 520 + c * 8] = *(const uint4*)&wsh[(size_t)(g * 512 + hid0 + h) * 512 + c * 8];
  }
  const int hid = hid0 + ni * 16 + l15;
  float br[4];
#pragma unroll
  for (int g = 0; g < 4; ++g) br[g] = b_s[g * 512 + hid];

  for (int i = tid; i < 1024; i += 256)
    hb[(size_t)(rows0 + (i >> 5)) * 512 + hid0 + (i & 31)] = (bf16_t)0.f;

  float cst[4] = {0.f, 0.f, 0.f, 0.f};
  const f32x4 z4 = {0.f, 0.f, 0.f, 0.f};
  gbar(bar, bar + 1, 128);

  for (int t = 0; t < 128; ++t) {
    const int cur = t & 1, nxt = cur ^ 1;
    const bf16_t* hr = hb + (size_t)cur * 131072 + (size_t)(rows0 + mi * 16 + l15) * 512;
    f32x4 acc[4];
#pragma unroll
    for (int g = 0; g < 4; ++g) acc[g] = z4;

#pragma unroll
    for (int ks = 0; ks < 16; ++ks) {         // K = 512
      bf16x8 a = *(const bf16x8*)&hr[ks * 32 + quad * 8];
#pragma unroll
      for (int g = 0; g < 4; ++g) {
        bf16x8 b = *(const bf16x8*)&Ws[(g * 32 + ni * 16 + l15) * 520 + ks * 32 + quad * 8];
        acc[g] = MFMA_BF16(a, b, acc[g]);
      }
    }

    const int row = rows0 + mi * 16 + quad * 4;
#pragma unroll
    for (int p = 0; p < 4; ++p) {
      const size_t gb = ((size_t)(row + p) * 128 + t) * 2048 + hid;
      float Pi = acc[0][p] + (float)gs[gb] + br[0];
      float Pf = acc[1][p] + (float)gs[gb + 512] + br[1];
      float Pg = acc[2][p] + (float)gs[gb + 1024] + br[2];
      float Po = acc[3][p] + (float)gs[gb + 1536] + br[3];
      float cc = sigm_(Pf) * cst[p] + sigm_(Pi) * tanh_(Pg);
      cst[p] = cc;
      float hv = sigm_(Po) * tanh_(cc);
      hb[(size_t)nxt * 131072 + (size_t)(row + p) * 512 + hid] = (bf16_t)hv;
      if (t == 127) hT[(size_t)(row + p) * 512 + hid] = hv;
    }
    gbar(bar, bar + 1, 128);
  }
}

// ------------------------------- emissions ---------------------------------
__global__ void emis_k(const float* __restrict__ hT, const float* __restrict__ lin_w,
                       const float* __restrict__ lin_b, float* __restrict__ em) {
  const int idx = blockIdx.x * 256 + threadIdx.x;
  const int s = idx >> 4, c = idx & 15;
  const float4* h4 = (const float4*)(hT + (size_t)s * 512);
  const float4* w4 = (const float4*)(lin_w + (size_t)c * 512);
  float acc = lin_b[c];
  for (int k = 0; k < 128; ++k) {
    float4 a = h4[k], b = w4[k];
    acc += a.x * b.x + a.y * b.y + a.z * b.z + a.w * b.w;
  }
  em[idx] = acc;
}

// ---------------------------------- CRF ------------------------------------
__global__ void crf_k(const float* __restrict__ em, const int* __restrict__ y,
                      const float* __restrict__ cs, const float* __restrict__ ce,
                      const float* __restrict__ tr, float* __restrict__ out) {
  __shared__ float alpha[16];
  __shared__ float trs[256];
  const int lane = threadIdx.x;
  const int i = lane & 15, jg = lane >> 4;

  for (int k = lane; k < 256; k += 64) trs[k] = tr[k];
  __syncthreads();

  float np = 0.f;
  for (int s = lane; s < 256; s += 64) np += em[s * 16 + y[s]];
  for (int s = lane + 1; s < 256; s += 64) np += trs[y[s - 1] * 16 + y[s]];
#pragma unroll
  for (int off = 32; off > 0; off >>= 1) np += __shfl_down(np, off, 64);

  if (lane < 16) alpha[lane] = cs[lane] + em[lane];
  __syncthreads();

  for (int s = 1; s < 256; ++s) {
    const float* e = em + s * 16;
    float v[4];
#pragma unroll
    for (int jj = 0; jj < 4; ++jj) v[jj] = alpha[i] + trs[i * 16 + (jj * 4 + jg)];
    float res[4];
#pragma unroll
    for (int jj = 0; jj < 4; ++jj) {
      float m = v[jj];
      m = fmaxf(m, __shfl_xor(m, 1, 64));
      m = fmaxf(m, __shfl_xor(m, 2, 64));
      m = fmaxf(m, __shfl_xor(m, 4, 64));
      m = fmaxf(m, __shfl_xor(m, 8, 64));
      float ex = __expf(v[jj] - m);
      ex += __shfl_xor(ex, 1, 64);
      ex += __shfl_xor(ex, 2, 64);
      ex += __shfl_xor(ex, 4, 64);
      ex += __shfl_xor(ex, 8, 64);
      res[jj] = m + __logf(ex) + e[jj * 4 + jg];
    }
#pragma unroll
    for (int jj = 0; jj < 4; ++jj)
      if (i == 0) alpha[jj * 4 + jg] = res[jj];
  }

  float v = (lane < 16) ? (alpha[lane] + ce[lane]) : -3.0e38f;
  float m = v;
#pragma unroll
  for (int off = 32; off > 0; off >>= 1) m = fmaxf(m, __shfl_xor(m, off, 64));
  float ex = __expf(v - m);
#pragma unroll
  for (int off = 32; off > 0; off >>= 1) ex += __shfl_xor(ex, off, 64);
  float denom = m + __logf(ex);

  if (lane == 0) {
    float num = np + cs[y[0]] + ce[y[255]];
    out[0] = num - denom;
  }
}

// ------------------------------ orchestration ------------------------------
extern "C" void kernel_launch(void* const* d_in, const int* in_sizes, int n_in,
                              void* d_out, int out_size, void* d_ws, size_t ws_size,
                              hipStream_t stream) {
  const float* x = (const float*)d_in[0];
  const int* y = (const int*)d_in[1];
  const float* w_ih_f = (const float*)d_in[3];
  const float* w_hh_f = (const float*)d_in[4];
  const float* b_f = (const float*)d_in[5];
  const float* w_ih_r = (const float*)d_in[6];
  const float* w_hh_r = (const float*)d_in[7];
  const float* b_r = (const float*)d_in[8];
  const float* w_ih_s = (const float*)d_in[9];
  const float* w_hh_s = (const float*)d_in[10];
  const float* b_s = (const float*)d_in[11];
  const float* lin_w = (const float*)d_in[12];
  const float* lin_b = (const float*)d_in[13];
  const float* crf_s = (const float*)d_in[14];
  const float* crf_e = (const float*)d_in[15];
  const float* crf_t = (const float*)d_in[16];

  char* ws = (char*)d_ws;
  size_t off = 0;
  auto take = [&](size_t bytes) {
    void* p = ws + off;
    off += (bytes + 255) & ~(size_t)255;
    return p;
  };
  bf16_t* Wx  = (bf16_t*)take((size_t)2048 * 768 * 2);
  bf16_t* Whh = (bf16_t*)take((size_t)2 * 1024 * 256 * 2);
  bf16_t* Wsi = (bf16_t*)take((size_t)2048 * 512 * 2);
  bf16_t* Wsh = (bf16_t*)take((size_t)2048 * 512 * 2);
  bf16_t* gx  = (bf16_t*)take((size_t)32768 * 2048 * 2);
  bf16_t* xb  = (bf16_t*)take((size_t)32768 * 768 * 2);   // 48MB region
  float* hT   = (float*)take((size_t)256 * 512 * 4);
  float* em   = (float*)take((size_t)4096 * 4);
  bf16_t* gs = gx;       // gx dead after lstm_fr
  bf16_t* hcat = xb;     // xb dead after gemm1; hcat = first 32MB of region
  // carve hb/bars out of the dead tail of the xb region (bytes 33.5MB..48MB),
  // live only after gemm1 has consumed xb — stays within R1's proven footprint
  char* tail = (char*)xb + 33554432;
  bf16_t* hb_fr = (bf16_t*)tail;                 // 2*2*256*256*2 = 512KB
  bf16_t* hb_s  = (bf16_t*)(tail + 524288);      // 2*256*512*2   = 512KB
  unsigned* bar = (unsigned*)(tail + 1048576);   // 8 uints
  (void)ws_size; (void)in_sizes; (void)n_in; (void)out_size;

  // phase 1: converts
  cvt4<<<2048, 256, 0, stream>>>(x, xb, 32768 * 768 / 4);
  cvt4<<<64, 256, 0, stream>>>(w_ih_f, Wx, 786432 / 4);
  cvt4<<<64, 256, 0, stream>>>(w_ih_r, Wx + 786432, 786432 / 4);
  cvt4<<<32, 256, 0, stream>>>(w_hh_f, Whh, 262144 / 4);
  cvt4<<<32, 256, 0, stream>>>(w_hh_r, Whh + 262144, 262144 / 4);
  cvt4<<<64, 256, 0, stream>>>(w_ih_s, Wsi, 1048576 / 4);
  cvt4<<<64, 256, 0, stream>>>(w_hh_s, Wsh, 1048576 / 4);

  // phase 2: input gates for fwd+rev   (M=32768, N=2048, K=768)
  gemm_bt<<<4096, 256, 0, stream>>>(xb, Wx, gx, 32768, 2048, 768);

  // barriers live in xb tail — init only after gemm1 is done with xb
  init_bar<<<1, 64, 0, stream>>>(bar);

  // phase 3: fwd/rev recurrences -> h_cat
  lstm_fr<<<128, 256, 0, stream>>>(gx, Whh, b_f, b_r, hcat, hb_fr, bar);

  // phase 4: sentence input gates     (M=32768, N=2048, K=512)
  gemm_bt<<<4096, 256, 0, stream>>>(hcat, Wsi, gs, 32768, 2048, 512);

  // phase 5: sentence recurrence -> hT
  lstm_s<<<128, 256, 0, stream>>>(gs, Wsh, b_s, hT, hb_s, bar + 2);

  // phase 6: emissions + CRF
  emis_k<<<16, 256, 0, stream>>>(hT, lin_w, lin_b, em);
  crf_k<<<1, 64, 0, stream>>>(em, y, crf_s, crf_e, crf_t, (float*)d_out);
}